// Round 8
// baseline (187.706 us; speedup 1.0000x reference)
//
#include <hip/hip_runtime.h>
#include <hip/hip_bf16.h>

#define DIM   512
#define QKVD  1536
#define HEADS 8
#define HD    64
#define NSEQ  4096
#define LDP   72    // 144B row stride, bank-stride 4 mod 32 -> conflict-free b128
#define LDPK  72
#define LDPV  136   // 272B stride, conflict-free b128
#define SCALE_LOG2E 0.18033688011112042f   // 0.125 * log2(e), folded into Q

typedef float  f32x4  __attribute__((ext_vector_type(4)));
typedef __bf16 bf16x8 __attribute__((ext_vector_type(8)));
typedef __bf16 bf16x4 __attribute__((ext_vector_type(4)));
typedef short  s16x4  __attribute__((ext_vector_type(4)));

static __device__ inline f32x4 mfma32(bf16x8 a, bf16x8 b, f32x4 c) {
  return __builtin_amdgcn_mfma_f32_16x16x32_bf16(a, b, c, 0, 0, 0);
}
static __device__ inline s16x4 pack_bf16(f32x4 v) {
  bf16x4 b = __builtin_convertvector(v, bf16x4);
  return __builtin_bit_cast(s16x4, b);
}

__global__ __launch_bounds__(256) void cvt_bf16(const float* __restrict__ s,
                                                __bf16* __restrict__ d, int n4) {
  int i = blockIdx.x * 256 + threadIdx.x;
  if (i >= n4) return;
  f32x4 v = ((const f32x4*)s)[i];
  *(bf16x4*)(d + 4 * (size_t)i) = __builtin_convertvector(v, bf16x4);
}

// 128x128-tile GEMM, register-prefetch: C[m][1536] = A[8192x512]*Bw^T + bias;
// Q columns scaled by 0.125*log2e. Grid (nt=12, mt=64): same-mt blocks are
// dispatch-adjacent -> A-strip (128KB) L2-resident per XCD.
__global__ __launch_bounds__(256) void gemm_qkv(const __bf16* __restrict__ A,
                                                const __bf16* __restrict__ Bw,
                                                const float* __restrict__ bias,
                                                __bf16* __restrict__ C) {
  const int nt = blockIdx.x;   // 0..11
  const int mt = blockIdx.y;   // 0..63
  __shared__ __bf16 As[128 * LDP];
  __shared__ __bf16 Bs[128 * LDP];
  const int tid = threadIdx.x, w = tid >> 6, lane = tid & 63;
  const int l16 = lane & 15, quad = lane >> 4;

  int row[4], c8[4];
#pragma unroll
  for (int i = 0; i < 4; ++i) { int ch = tid + i * 256; row[i] = ch >> 3; c8[i] = (ch & 7) << 3; }

  bf16x8 pa[4], pb[4];
#pragma unroll
  for (int i = 0; i < 4; ++i) {
    pa[i] = *(const bf16x8*)(A + (size_t)(mt * 128 + row[i]) * DIM + c8[i]);
    pb[i] = *(const bf16x8*)(Bw + (size_t)(nt * 128 + row[i]) * DIM + c8[i]);
  }

  f32x4 acc[2][8] = {};
  for (int kt = 0; kt < 8; ++kt) {
    __syncthreads();
#pragma unroll
    for (int i = 0; i < 4; ++i) {
      *(bf16x8*)(As + row[i] * LDP + c8[i]) = pa[i];
      *(bf16x8*)(Bs + row[i] * LDP + c8[i]) = pb[i];
    }
    __syncthreads();
    if (kt < 7) {
#pragma unroll
      for (int i = 0; i < 4; ++i) {
        pa[i] = *(const bf16x8*)(A + (size_t)(mt * 128 + row[i]) * DIM + (kt + 1) * 64 + c8[i]);
        pb[i] = *(const bf16x8*)(Bw + (size_t)(nt * 128 + row[i]) * DIM + (kt + 1) * 64 + c8[i]);
      }
    }
#pragma unroll
    for (int c = 0; c < 2; ++c) {
      bf16x8 a[2];
#pragma unroll
      for (int mtt = 0; mtt < 2; ++mtt)
        a[mtt] = *(const bf16x8*)(As + (w * 32 + mtt * 16 + l16) * LDP + quad * 8 + c * 32);
#pragma unroll
      for (int ct = 0; ct < 8; ++ct) {
        bf16x8 bb = *(const bf16x8*)(Bs + (ct * 16 + l16) * LDP + quad * 8 + c * 32);
#pragma unroll
        for (int mtt = 0; mtt < 2; ++mtt)
          acc[mtt][ct] = mfma32(a[mtt], bb, acc[mtt][ct]);
      }
    }
  }
  const float sc = (nt < 4) ? SCALE_LOG2E : 1.0f;   // nt 0..3 = Q columns
#pragma unroll
  for (int ct = 0; ct < 8; ++ct) {
    int oc = nt * 128 + ct * 16 + l16;
    float bv = bias[oc];
#pragma unroll
    for (int mtt = 0; mtt < 2; ++mtt)
#pragma unroll
      for (int r = 0; r < 4; ++r) {
        int mrow = mt * 128 + w * 32 + mtt * 16 + quad * 4 + r;
        C[(size_t)mrow * QKVD + oc] = (__bf16)((acc[mtt][ct][r] + bv) * sc);
      }
  }
}

// 128x64-tile GEMM, fp32 output: out = A[8192x512]*Bw[512x512]^T + bias.
// Grid (nt=8, mt=64) for A-strip L2 locality.
__global__ __launch_bounds__(256) void gemm_proj(const __bf16* __restrict__ A,
                                                 const __bf16* __restrict__ Bw,
                                                 const float* __restrict__ bias,
                                                 float* __restrict__ C) {
  const int nt = blockIdx.x;   // 0..7
  const int mt = blockIdx.y;   // 0..63
  __shared__ __bf16 As[128 * LDP];
  __shared__ __bf16 Bs[64 * LDP];
  const int tid = threadIdx.x, w = tid >> 6, lane = tid & 63;
  const int l16 = lane & 15, quad = lane >> 4;

  int arow[4], ac8[4], brow[2], bc8[2];
#pragma unroll
  for (int i = 0; i < 4; ++i) { int ch = tid + i * 256; arow[i] = ch >> 3; ac8[i] = (ch & 7) << 3; }
#pragma unroll
  for (int i = 0; i < 2; ++i) { int ch = tid + i * 256; brow[i] = ch >> 3; bc8[i] = (ch & 7) << 3; }

  bf16x8 pa[4], pb[2];
#pragma unroll
  for (int i = 0; i < 4; ++i)
    pa[i] = *(const bf16x8*)(A + (size_t)(mt * 128 + arow[i]) * DIM + ac8[i]);
#pragma unroll
  for (int i = 0; i < 2; ++i)
    pb[i] = *(const bf16x8*)(Bw + (size_t)(nt * 64 + brow[i]) * DIM + bc8[i]);

  f32x4 acc[2][4] = {};
  for (int kt = 0; kt < 8; ++kt) {
    __syncthreads();
#pragma unroll
    for (int i = 0; i < 4; ++i) *(bf16x8*)(As + arow[i] * LDP + ac8[i]) = pa[i];
#pragma unroll
    for (int i = 0; i < 2; ++i) *(bf16x8*)(Bs + brow[i] * LDP + bc8[i]) = pb[i];
    __syncthreads();
    if (kt < 7) {
#pragma unroll
      for (int i = 0; i < 4; ++i)
        pa[i] = *(const bf16x8*)(A + (size_t)(mt * 128 + arow[i]) * DIM + (kt + 1) * 64 + ac8[i]);
#pragma unroll
      for (int i = 0; i < 2; ++i)
        pb[i] = *(const bf16x8*)(Bw + (size_t)(nt * 64 + brow[i]) * DIM + (kt + 1) * 64 + bc8[i]);
    }
#pragma unroll
    for (int c = 0; c < 2; ++c) {
      bf16x8 a[2];
#pragma unroll
      for (int mtt = 0; mtt < 2; ++mtt)
        a[mtt] = *(const bf16x8*)(As + (w * 32 + mtt * 16 + l16) * LDP + quad * 8 + c * 32);
#pragma unroll
      for (int ct = 0; ct < 4; ++ct) {
        bf16x8 bb = *(const bf16x8*)(Bs + (ct * 16 + l16) * LDP + quad * 8 + c * 32);
#pragma unroll
        for (int mtt = 0; mtt < 2; ++mtt)
          acc[mtt][ct] = mfma32(a[mtt], bb, acc[mtt][ct]);
      }
    }
  }
#pragma unroll
  for (int ct = 0; ct < 4; ++ct) {
    int oc = nt * 64 + ct * 16 + l16;
    float bv = bias[oc];
#pragma unroll
    for (int mtt = 0; mtt < 2; ++mtt)
#pragma unroll
      for (int r = 0; r < 4; ++r) {
        int mrow = mt * 128 + w * 32 + mtt * 16 + quad * 4 + r;
        C[(size_t)mrow * DIM + oc] = acc[mtt][ct][r] + bv;
      }
  }
}

// V columns of qkvC -> Vt[bh][d][perm(n)] (key-permuted within 64-key blocks).
__global__ __launch_bounds__(256) void transpose_v(const __bf16* __restrict__ QKV,
                                                   __bf16* __restrict__ Vt) {
  const int nt = blockIdx.x;   // 0..63
  const int bh = blockIdx.y;   // 0..15
  const int b = bh >> 3, h = bh & 7;
  __shared__ __bf16 T[64 * LDP];
  const int tid = threadIdx.x;
  const __bf16* src = QKV + (size_t)(b * NSEQ + nt * 64) * QKVD + 1024 + h * 64;
#pragma unroll
  for (int i = 0; i < 2; ++i) {
    int ch = tid + i * 256, row = ch >> 3, c8 = (ch & 7) << 3;
    *(bf16x8*)(T + row * LDP + c8) = *(const bf16x8*)(src + (size_t)row * QKVD + c8);
  }
  __syncthreads();
  const int d = tid >> 2, t = tid & 3;
  const int g2 = t >> 1, m = t & 1;
  __bf16* dst = Vt + ((size_t)bh * HD + d) * NSEQ + nt * 64 + g2 * 32 + m * 4;
#pragma unroll
  for (int u = 0; u < 4; ++u) {
    bf16x4 o;
#pragma unroll
    for (int jj = 0; jj < 4; ++jj) o[jj] = T[(t * 16 + u * 4 + jj) * LDP + d];
    *(bf16x4*)(dst + u * 8) = o;
  }
}

// Flash attention v8 (= v7 compute, bh on blockIdx.x): 512-thread block = two
// 4-wave key-split groups; mt=4; max-free softmax; l via MFMA ones-column.
// XCD = bh%8 -> each XCD's L2 caches only its 2 bh's K/V (2 MB, fits 4 MB).
__global__ __launch_bounds__(512, 2) void attn_fused(const __bf16* __restrict__ QKV,
                                                     const __bf16* __restrict__ Vtp,
                                                     __bf16* __restrict__ Og) {
  const int bh = blockIdx.x;   // 0..15
  const int qt = blockIdx.y;   // 0..15 (256 q rows)
  const int b = bh >> 3, h = bh & 7;

  __shared__ __align__(16) char smem[81920];
  __bf16* KsAll  = (__bf16*)smem;               // [2][128*LDPK] = 36864 B
  __bf16* VtsAll = (__bf16*)(smem + 36864);     // [2][64*LDPV]  = 34816 B
  float*  Oex    = (float*)smem;                // 81920 B (after compute)

  const int tid = threadIdx.x, w = tid >> 6, lane = tid & 63;
  const int wg = w & 3, grp = w >> 2;
  const int l16 = lane & 15, quad = lane >> 4;
  const int g256 = tid & 255;

  __bf16* Ks  = KsAll + grp * (128 * LDPK);
  __bf16* Vts = VtsAll + grp * (64 * LDPV);

  const __bf16* Qb = QKV + (size_t)(b * NSEQ + qt * 256) * QKVD + h * 64;
  const __bf16* Kb = QKV + ((size_t)b * NSEQ + (size_t)grp * 2048) * QKVD + 512 + h * 64;
  const __bf16* Vp = Vtp + (size_t)bh * HD * NSEQ + grp * 2048;

  // Q fragments (one-time); both groups load the same rows
  bf16x8 aq[4][2];
#pragma unroll
  for (int mt = 0; mt < 4; ++mt)
#pragma unroll
    for (int c = 0; c < 2; ++c)
      aq[mt][c] = *(const bf16x8*)(Qb + (size_t)(wg * 64 + mt * 16 + l16) * QKVD +
                                   quad * 8 + c * 32);

  int krow[4], kc8[4], vd[4], vp8[4];
#pragma unroll
  for (int i = 0; i < 4; ++i) {
    int ch = g256 + i * 256;
    krow[i] = ch >> 3; kc8[i] = (ch & 7) << 3;
    vd[i] = ch >> 4;   vp8[i] = (ch & 15) << 3;
  }

  bf16x8 kreg[4], vreg[4];
#pragma unroll
  for (int i = 0; i < 4; ++i) {
    kreg[i] = *(const bf16x8*)(Kb + (size_t)krow[i] * QKVD + kc8[i]);
    vreg[i] = *(const bf16x8*)(Vp + (size_t)vd[i] * NSEQ + vp8[i]);
  }

  bf16x8 ones;
#pragma unroll
  for (int j = 0; j < 8; ++j) ones[j] = (__bf16)1.0f;

  f32x4 Oacc[4][5] = {};   // dt 0..3 = O, dt 4 = l (ones-column)

  for (int kt = 0; kt < 16; ++kt) {
    __syncthreads();
#pragma unroll
    for (int i = 0; i < 4; ++i) {
      *(bf16x8*)(Ks + krow[i] * LDPK + kc8[i]) = kreg[i];
      *(bf16x8*)(Vts + vd[i] * LDPV + vp8[i]) = vreg[i];
    }
    __syncthreads();

    if (kt + 1 < 16) {
      const __bf16* Kn = Kb + (size_t)(kt + 1) * 128 * QKVD;
      const __bf16* Vn = Vp + (size_t)(kt + 1) * 128;
#pragma unroll
      for (int i = 0; i < 4; ++i) {
        kreg[i] = *(const bf16x8*)(Kn + (size_t)krow[i] * QKVD + kc8[i]);
        vreg[i] = *(const bf16x8*)(Vn + (size_t)vd[i] * NSEQ + vp8[i]);
      }
    }

#pragma unroll
    for (int g = 0; g < 4; ++g) {
      bf16x8 kb[2][2];
#pragma unroll
      for (int e = 0; e < 2; ++e)
#pragma unroll
        for (int c = 0; c < 2; ++c)
          kb[e][c] = *(const bf16x8*)(Ks + ((2 * g + e) * 16 + l16) * LDPK +
                                      quad * 8 + c * 32);
      bf16x8 ap[4];
#pragma unroll
      for (int mt = 0; mt < 4; ++mt) {
        f32x4 a0 = {}, a1 = {};
        a0 = mfma32(kb[0][0], aq[mt][0], a0);
        a0 = mfma32(kb[0][1], aq[mt][1], a0);
        a1 = mfma32(kb[1][0], aq[mt][0], a1);
        a1 = mfma32(kb[1][1], aq[mt][1], a1);
        f32x4 e0, e1;
#pragma unroll
        for (int r = 0; r < 4; ++r) {
          e0[r] = __builtin_amdgcn_exp2f(a0[r]);
          e1[r] = __builtin_amdgcn_exp2f(a1[r]);
        }
        ap[mt] = __builtin_bit_cast(bf16x8,
            __builtin_shufflevector(pack_bf16(e0), pack_bf16(e1), 0, 1, 2, 3, 4, 5, 6, 7));
      }
#pragma unroll
      for (int dt = 0; dt < 4; ++dt) {
        bf16x8 bv = *(const bf16x8*)(Vts + (dt * 16 + l16) * LDPV + g * 32 + quad * 8);
#pragma unroll
        for (int mt = 0; mt < 4; ++mt)
          Oacc[mt][dt] = mfma32(ap[mt], bv, Oacc[mt][dt]);
      }
#pragma unroll
      for (int mt = 0; mt < 4; ++mt)
        Oacc[mt][4] = mfma32(ap[mt], ones, Oacc[mt][4]);   // l column
    }
  }

  // combine group partials via LDS (staging buffers are dead now)
  __syncthreads();
  if (grp == 1) {
#pragma unroll
    for (int mt = 0; mt < 4; ++mt)
#pragma unroll
      for (int dt = 0; dt < 5; ++dt)
        *(f32x4*)(Oex + (((wg * 4 + mt) * 5 + dt) << 8) + (lane << 2)) = Oacc[mt][dt];
  }
  __syncthreads();
  if (grp == 0) {
#pragma unroll
    for (int mt = 0; mt < 4; ++mt) {
#pragma unroll
      for (int dt = 0; dt < 5; ++dt)
        Oacc[mt][dt] += *(const f32x4*)(Oex + (((wg * 4 + mt) * 5 + dt) << 8) + (lane << 2));
#pragma unroll
      for (int r = 0; r < 4; ++r) {
        float inv = 1.0f / Oacc[mt][4][r];   // l for q-row quad*4+r
        int n = qt * 256 + wg * 64 + mt * 16 + quad * 4 + r;
        size_t base = ((size_t)b * NSEQ + n) * DIM + (size_t)h * HD;
#pragma unroll
        for (int dt = 0; dt < 4; ++dt)
          Og[base + dt * 16 + l16] = (__bf16)(Oacc[mt][dt][r] * inv);
      }
    }
  }
}

extern "C" void kernel_launch(void* const* d_in, const int* in_sizes, int n_in,
                              void* d_out, int out_size, void* d_ws, size_t ws_size,
                              hipStream_t stream) {
  const float* x      = (const float*)d_in[0];   // [2,4096,512]
  const float* qkv_w  = (const float*)d_in[1];   // [1536,512]
  const float* qkv_b  = (const float*)d_in[2];   // [1536]
  const float* proj_w = (const float*)d_in[3];   // [512,512]
  const float* proj_b = (const float*)d_in[4];   // [512]
  float* out = (float*)d_out;                    // [2,4096,512] fp32

  char* ws = (char*)d_ws;
  __bf16* xb    = (__bf16*)(ws);                 // 8 MB  x in bf16 (dead after gemm_qkv)
  __bf16* Vtw   = (__bf16*)(ws);                 // 8 MB  [B,H,HD,N] permuted (reuses xb)
  __bf16* qkvC  = (__bf16*)(ws + 8388608);       // 24 MB [8192][1536]
  __bf16* wqkv  = (__bf16*)(ws + 33554432);      // 1.5 MB
  __bf16* wproj = (__bf16*)(ws + 35127296);      // 0.5 MB
  __bf16* Ob    = (__bf16*)(ws + 35651584);      // 8 MB  context [m][512]
  // total 44,040,192 B

  cvt_bf16<<<4096, 256, 0, stream>>>(x, xb, 1048576);
  cvt_bf16<<<768, 256, 0, stream>>>(qkv_w, wqkv, 196608);
  cvt_bf16<<<256, 256, 0, stream>>>(proj_w, wproj, 65536);

  gemm_qkv<<<dim3(12, 64), 256, 0, stream>>>(xb, wqkv, qkv_b, qkvC);
  transpose_v<<<dim3(64, 16), 256, 0, stream>>>(qkvC, Vtw);
  attn_fused<<<dim3(16, 16), 512, 0, stream>>>(qkvC, Vtw, Ob);
  gemm_proj<<<dim3(8, 64), 256, 0, stream>>>(Ob, wproj, proj_b, out);
}

// Round 9
// 180.115 us; speedup vs baseline: 1.0421x; 1.0421x over previous
//
#include <hip/hip_runtime.h>
#include <hip/hip_bf16.h>

#define DIM   512
#define QKD   1024   // Q/K buffer row stride (V no longer stored row-major)
#define HEADS 8
#define HD    64
#define NSEQ  4096
#define LDP   72    // 144B row stride, bank-stride 4 mod 32 -> conflict-free b128
#define LDPK  72
#define LDPV  136   // 272B stride, conflict-free b128
#define LDPM  136   // V-transpose repack tile [oc][m] row stride (16B-aligned rows)
#define SCALE_LOG2E 0.18033688011112042f   // 0.125 * log2(e), folded into Q

typedef float  f32x4  __attribute__((ext_vector_type(4)));
typedef __bf16 bf16x8 __attribute__((ext_vector_type(8)));
typedef __bf16 bf16x4 __attribute__((ext_vector_type(4)));
typedef short  s16x4  __attribute__((ext_vector_type(4)));

static __device__ inline f32x4 mfma32(bf16x8 a, bf16x8 b, f32x4 c) {
  return __builtin_amdgcn_mfma_f32_16x16x32_bf16(a, b, c, 0, 0, 0);
}
static __device__ inline s16x4 pack_bf16(f32x4 v) {
  bf16x4 b = __builtin_convertvector(v, bf16x4);
  return __builtin_bit_cast(s16x4, b);
}

// One conversion kernel for all three fp32->bf16 inputs (saves 2 launches).
__global__ __launch_bounds__(256) void cvt_all(const float* __restrict__ x,
                                               const float* __restrict__ qw,
                                               const float* __restrict__ pw,
                                               __bf16* __restrict__ xb,
                                               __bf16* __restrict__ wqkv,
                                               __bf16* __restrict__ wproj) {
  int i = blockIdx.x * 256 + threadIdx.x;   // f32x4 unit index, 0..1310719
  const float* s; __bf16* d; int off;
  if (i < 1048576)      { s = x;  d = xb;    off = i; }
  else if (i < 1245184) { s = qw; d = wqkv;  off = i - 1048576; }
  else                  { s = pw; d = wproj; off = i - 1245184; }
  f32x4 v = *(const f32x4*)(s + 4 * (size_t)off);
  *(bf16x4*)(d + 4 * (size_t)off) = __builtin_convertvector(v, bf16x4);
}

// 128x128-tile GEMM, register-prefetch. nt 0..7: Q/K columns -> qkC[m][1024]
// (Q scaled by 0.125*log2e). nt 8..11: V columns -> written TRANSPOSED and
// key-PERMUTED straight to Vt[bh][d][perm(n)] via an LDS repack (replaces the
// separate transpose_v kernel).
__global__ __launch_bounds__(256) void gemm_qkv(const __bf16* __restrict__ A,
                                                const __bf16* __restrict__ Bw,
                                                const float* __restrict__ bias,
                                                __bf16* __restrict__ C,
                                                __bf16* __restrict__ Vt) {
  const int nt = blockIdx.x;   // 0..11
  const int mt = blockIdx.y;   // 0..63
  __shared__ __align__(16) char smem[36864];
  __bf16* As = (__bf16*)smem;                    // 128*LDP = 18432 B
  __bf16* Bs = (__bf16*)(smem + 18432);          // 18432 B
  __bf16* T  = (__bf16*)smem;                    // 128*LDPM*2 = 34816 B (epilogue)
  const int tid = threadIdx.x, w = tid >> 6, lane = tid & 63;
  const int l16 = lane & 15, quad = lane >> 4;

  int row[4], c8[4];
#pragma unroll
  for (int i = 0; i < 4; ++i) { int ch = tid + i * 256; row[i] = ch >> 3; c8[i] = (ch & 7) << 3; }

  bf16x8 pa[4], pb[4];
#pragma unroll
  for (int i = 0; i < 4; ++i) {
    pa[i] = *(const bf16x8*)(A + (size_t)(mt * 128 + row[i]) * DIM + c8[i]);
    pb[i] = *(const bf16x8*)(Bw + (size_t)(nt * 128 + row[i]) * DIM + c8[i]);
  }

  f32x4 acc[2][8] = {};
  for (int kt = 0; kt < 8; ++kt) {
    __syncthreads();
#pragma unroll
    for (int i = 0; i < 4; ++i) {
      *(bf16x8*)(As + row[i] * LDP + c8[i]) = pa[i];
      *(bf16x8*)(Bs + row[i] * LDP + c8[i]) = pb[i];
    }
    __syncthreads();
    if (kt < 7) {
#pragma unroll
      for (int i = 0; i < 4; ++i) {
        pa[i] = *(const bf16x8*)(A + (size_t)(mt * 128 + row[i]) * DIM + (kt + 1) * 64 + c8[i]);
        pb[i] = *(const bf16x8*)(Bw + (size_t)(nt * 128 + row[i]) * DIM + (kt + 1) * 64 + c8[i]);
      }
    }
#pragma unroll
    for (int c = 0; c < 2; ++c) {
      bf16x8 a[2];
#pragma unroll
      for (int mtt = 0; mtt < 2; ++mtt)
        a[mtt] = *(const bf16x8*)(As + (w * 32 + mtt * 16 + l16) * LDP + quad * 8 + c * 32);
#pragma unroll
      for (int ct = 0; ct < 8; ++ct) {
        bf16x8 bb = *(const bf16x8*)(Bs + (ct * 16 + l16) * LDP + quad * 8 + c * 32);
#pragma unroll
        for (int mtt = 0; mtt < 2; ++mtt)
          acc[mtt][ct] = mfma32(a[mtt], bb, acc[mtt][ct]);
      }
    }
  }

  if (nt < 8) {
    // Q/K epilogue: row-major into qkC[m][1024]
    const float sc = (nt < 4) ? SCALE_LOG2E : 1.0f;
#pragma unroll
    for (int ct = 0; ct < 8; ++ct) {
      int oc = nt * 128 + ct * 16 + l16;
      float bv = bias[oc];
#pragma unroll
      for (int mtt = 0; mtt < 2; ++mtt)
#pragma unroll
        for (int r = 0; r < 4; ++r) {
          int mrow = mt * 128 + w * 32 + mtt * 16 + quad * 4 + r;
          C[(size_t)mrow * QKD + oc] = (__bf16)((acc[mtt][ct][r] + bv) * sc);
        }
    }
  } else {
    // V epilogue: bias, repack to LDS [oc_local][m_local], then write
    // Vt[bh][d][perm(n)] coalesced-ish (replaces transpose_v kernel).
    __syncthreads();   // As/Bs dead, reuse as T
#pragma unroll
    for (int ct = 0; ct < 8; ++ct) {
      int oc_l = ct * 16 + l16;
      float bv = bias[1024 + (nt - 8) * 128 + oc_l];
#pragma unroll
      for (int mtt = 0; mtt < 2; ++mtt) {
        f32x4 v = acc[mtt][ct];
#pragma unroll
        for (int r = 0; r < 4; ++r) v[r] += bv;
        *(bf16x4*)(T + oc_l * LDPM + w * 32 + mtt * 16 + quad * 4) =
            __builtin_convertvector(v, bf16x4);
      }
    }
    __syncthreads();
    // read back: thread -> one oc_local row, 64 consecutive m (one 64-key block)
    const int oc_l = tid >> 1, mh = (tid & 1) * 64;
    const int d = oc_l & 63;
    const int h = 2 * (nt - 8) + (oc_l >> 6);
    const int n0 = mt * 128 + mh;            // start of this 64-key block
    const int b = n0 >> 12;
    const int bh = b * HEADS + h;
    bf16x8 o[8];
#pragma unroll
    for (int j = 0; j < 8; ++j)
      o[j] = *(const bf16x8*)(T + oc_l * LDPM + mh + j * 8);
    __bf16* dst = Vt + ((size_t)bh * HD + d) * NSEQ + (n0 & 4095);
#pragma unroll
    for (int j = 0; j < 8; ++j)
#pragma unroll
      for (int ih = 0; ih < 2; ++ih) {
        int e = 2 * j + ih;
        int off = (j >> 2) * 32 + ((e >> 2) & 1) * 4 + (e & 3) * 8;
        bf16x4 val;
#pragma unroll
        for (int d3 = 0; d3 < 4; ++d3) val[d3] = o[j][ih * 4 + d3];
        *(bf16x4*)(dst + off) = val;
      }
  }
}

// 128x64-tile GEMM, fp32 output: out = A[8192x512]*Bw[512x512]^T + bias.
__global__ __launch_bounds__(256) void gemm_proj(const __bf16* __restrict__ A,
                                                 const __bf16* __restrict__ Bw,
                                                 const float* __restrict__ bias,
                                                 float* __restrict__ C) {
  const int nt = blockIdx.x;   // 0..7
  const int mt = blockIdx.y;   // 0..63
  __shared__ __bf16 As[128 * LDP];
  __shared__ __bf16 Bs[64 * LDP];
  const int tid = threadIdx.x, w = tid >> 6, lane = tid & 63;
  const int l16 = lane & 15, quad = lane >> 4;

  int arow[4], ac8[4], brow[2], bc8[2];
#pragma unroll
  for (int i = 0; i < 4; ++i) { int ch = tid + i * 256; arow[i] = ch >> 3; ac8[i] = (ch & 7) << 3; }
#pragma unroll
  for (int i = 0; i < 2; ++i) { int ch = tid + i * 256; brow[i] = ch >> 3; bc8[i] = (ch & 7) << 3; }

  bf16x8 pa[4], pb[2];
#pragma unroll
  for (int i = 0; i < 4; ++i)
    pa[i] = *(const bf16x8*)(A + (size_t)(mt * 128 + arow[i]) * DIM + ac8[i]);
#pragma unroll
  for (int i = 0; i < 2; ++i)
    pb[i] = *(const bf16x8*)(Bw + (size_t)(nt * 64 + brow[i]) * DIM + bc8[i]);

  f32x4 acc[2][4] = {};
  for (int kt = 0; kt < 8; ++kt) {
    __syncthreads();
#pragma unroll
    for (int i = 0; i < 4; ++i) *(bf16x8*)(As + arow[i] * LDP + ac8[i]) = pa[i];
#pragma unroll
    for (int i = 0; i < 2; ++i) *(bf16x8*)(Bs + brow[i] * LDP + bc8[i]) = pb[i];
    __syncthreads();
    if (kt < 7) {
#pragma unroll
      for (int i = 0; i < 4; ++i)
        pa[i] = *(const bf16x8*)(A + (size_t)(mt * 128 + arow[i]) * DIM + (kt + 1) * 64 + ac8[i]);
#pragma unroll
      for (int i = 0; i < 2; ++i)
        pb[i] = *(const bf16x8*)(Bw + (size_t)(nt * 64 + brow[i]) * DIM + (kt + 1) * 64 + bc8[i]);
    }
#pragma unroll
    for (int c = 0; c < 2; ++c) {
      bf16x8 a[2];
#pragma unroll
      for (int mtt = 0; mtt < 2; ++mtt)
        a[mtt] = *(const bf16x8*)(As + (w * 32 + mtt * 16 + l16) * LDP + quad * 8 + c * 32);
#pragma unroll
      for (int ct = 0; ct < 4; ++ct) {
        bf16x8 bb = *(const bf16x8*)(Bs + (ct * 16 + l16) * LDP + quad * 8 + c * 32);
#pragma unroll
        for (int mtt = 0; mtt < 2; ++mtt)
          acc[mtt][ct] = mfma32(a[mtt], bb, acc[mtt][ct]);
      }
    }
  }
#pragma unroll
  for (int ct = 0; ct < 4; ++ct) {
    int oc = nt * 64 + ct * 16 + l16;
    float bv = bias[oc];
#pragma unroll
    for (int mtt = 0; mtt < 2; ++mtt)
#pragma unroll
      for (int r = 0; r < 4; ++r) {
        int mrow = mt * 128 + w * 32 + mtt * 16 + quad * 4 + r;
        C[(size_t)mrow * DIM + oc] = acc[mtt][ct][r] + bv;
      }
  }
}

// Flash attention (unchanged from R8): 512-thread block = two 4-wave key-split
// groups; mt=4; max-free softmax; l via MFMA ones-column; bh on blockIdx.x.
__global__ __launch_bounds__(512, 2) void attn_fused(const __bf16* __restrict__ QKV,
                                                     const __bf16* __restrict__ Vtp,
                                                     __bf16* __restrict__ Og) {
  const int bh = blockIdx.x;   // 0..15
  const int qt = blockIdx.y;   // 0..15 (256 q rows)
  const int b = bh >> 3, h = bh & 7;

  __shared__ __align__(16) char smem[81920];
  __bf16* KsAll  = (__bf16*)smem;               // [2][128*LDPK] = 36864 B
  __bf16* VtsAll = (__bf16*)(smem + 36864);     // [2][64*LDPV]  = 34816 B
  float*  Oex    = (float*)smem;                // 81920 B (after compute)

  const int tid = threadIdx.x, w = tid >> 6, lane = tid & 63;
  const int wg = w & 3, grp = w >> 2;
  const int l16 = lane & 15, quad = lane >> 4;
  const int g256 = tid & 255;

  __bf16* Ks  = KsAll + grp * (128 * LDPK);
  __bf16* Vts = VtsAll + grp * (64 * LDPV);

  const __bf16* Qb = QKV + (size_t)(b * NSEQ + qt * 256) * QKD + h * 64;
  const __bf16* Kb = QKV + ((size_t)b * NSEQ + (size_t)grp * 2048) * QKD + 512 + h * 64;
  const __bf16* Vp = Vtp + (size_t)bh * HD * NSEQ + grp * 2048;

  bf16x8 aq[4][2];
#pragma unroll
  for (int mt = 0; mt < 4; ++mt)
#pragma unroll
    for (int c = 0; c < 2; ++c)
      aq[mt][c] = *(const bf16x8*)(Qb + (size_t)(wg * 64 + mt * 16 + l16) * QKD +
                                   quad * 8 + c * 32);

  int krow[4], kc8[4], vd[4], vp8[4];
#pragma unroll
  for (int i = 0; i < 4; ++i) {
    int ch = g256 + i * 256;
    krow[i] = ch >> 3; kc8[i] = (ch & 7) << 3;
    vd[i] = ch >> 4;   vp8[i] = (ch & 15) << 3;
  }

  bf16x8 kreg[4], vreg[4];
#pragma unroll
  for (int i = 0; i < 4; ++i) {
    kreg[i] = *(const bf16x8*)(Kb + (size_t)krow[i] * QKD + kc8[i]);
    vreg[i] = *(const bf16x8*)(Vp + (size_t)vd[i] * NSEQ + vp8[i]);
  }

  bf16x8 ones;
#pragma unroll
  for (int j = 0; j < 8; ++j) ones[j] = (__bf16)1.0f;

  f32x4 Oacc[4][5] = {};   // dt 0..3 = O, dt 4 = l (ones-column)

  for (int kt = 0; kt < 16; ++kt) {
    __syncthreads();
#pragma unroll
    for (int i = 0; i < 4; ++i) {
      *(bf16x8*)(Ks + krow[i] * LDPK + kc8[i]) = kreg[i];
      *(bf16x8*)(Vts + vd[i] * LDPV + vp8[i]) = vreg[i];
    }
    __syncthreads();

    if (kt + 1 < 16) {
      const __bf16* Kn = Kb + (size_t)(kt + 1) * 128 * QKD;
      const __bf16* Vn = Vp + (size_t)(kt + 1) * 128;
#pragma unroll
      for (int i = 0; i < 4; ++i) {
        kreg[i] = *(const bf16x8*)(Kn + (size_t)krow[i] * QKD + kc8[i]);
        vreg[i] = *(const bf16x8*)(Vn + (size_t)vd[i] * NSEQ + vp8[i]);
      }
    }

#pragma unroll
    for (int g = 0; g < 4; ++g) {
      bf16x8 kb[2][2];
#pragma unroll
      for (int e = 0; e < 2; ++e)
#pragma unroll
        for (int c = 0; c < 2; ++c)
          kb[e][c] = *(const bf16x8*)(Ks + ((2 * g + e) * 16 + l16) * LDPK +
                                      quad * 8 + c * 32);
      bf16x8 ap[4];
#pragma unroll
      for (int mt = 0; mt < 4; ++mt) {
        f32x4 a0 = {}, a1 = {};
        a0 = mfma32(kb[0][0], aq[mt][0], a0);
        a0 = mfma32(kb[0][1], aq[mt][1], a0);
        a1 = mfma32(kb[1][0], aq[mt][0], a1);
        a1 = mfma32(kb[1][1], aq[mt][1], a1);
        f32x4 e0, e1;
#pragma unroll
        for (int r = 0; r < 4; ++r) {
          e0[r] = __builtin_amdgcn_exp2f(a0[r]);
          e1[r] = __builtin_amdgcn_exp2f(a1[r]);
        }
        ap[mt] = __builtin_bit_cast(bf16x8,
            __builtin_shufflevector(pack_bf16(e0), pack_bf16(e1), 0, 1, 2, 3, 4, 5, 6, 7));
      }
#pragma unroll
      for (int dt = 0; dt < 4; ++dt) {
        bf16x8 bv = *(const bf16x8*)(Vts + (dt * 16 + l16) * LDPV + g * 32 + quad * 8);
#pragma unroll
        for (int mt = 0; mt < 4; ++mt)
          Oacc[mt][dt] = mfma32(ap[mt], bv, Oacc[mt][dt]);
      }
#pragma unroll
      for (int mt = 0; mt < 4; ++mt)
        Oacc[mt][4] = mfma32(ap[mt], ones, Oacc[mt][4]);   // l column
    }
  }

  __syncthreads();
  if (grp == 1) {
#pragma unroll
    for (int mt = 0; mt < 4; ++mt)
#pragma unroll
      for (int dt = 0; dt < 5; ++dt)
        *(f32x4*)(Oex + (((wg * 4 + mt) * 5 + dt) << 8) + (lane << 2)) = Oacc[mt][dt];
  }
  __syncthreads();
  if (grp == 0) {
#pragma unroll
    for (int mt = 0; mt < 4; ++mt) {
#pragma unroll
      for (int dt = 0; dt < 5; ++dt)
        Oacc[mt][dt] += *(const f32x4*)(Oex + (((wg * 4 + mt) * 5 + dt) << 8) + (lane << 2));
#pragma unroll
      for (int r = 0; r < 4; ++r) {
        float inv = 1.0f / Oacc[mt][4][r];
        int n = qt * 256 + wg * 64 + mt * 16 + quad * 4 + r;
        size_t base = ((size_t)b * NSEQ + n) * DIM + (size_t)h * HD;
#pragma unroll
        for (int dt = 0; dt < 4; ++dt)
          Og[base + dt * 16 + l16] = (__bf16)(Oacc[mt][dt][r] * inv);
      }
    }
  }
}

extern "C" void kernel_launch(void* const* d_in, const int* in_sizes, int n_in,
                              void* d_out, int out_size, void* d_ws, size_t ws_size,
                              hipStream_t stream) {
  const float* x      = (const float*)d_in[0];   // [2,4096,512]
  const float* qkv_w  = (const float*)d_in[1];   // [1536,512]
  const float* qkv_b  = (const float*)d_in[2];   // [1536]
  const float* proj_w = (const float*)d_in[3];   // [512,512]
  const float* proj_b = (const float*)d_in[4];   // [512]
  float* out = (float*)d_out;                    // [2,4096,512] fp32

  char* ws = (char*)d_ws;
  __bf16* xb    = (__bf16*)(ws);                 // 8 MB  x in bf16
  __bf16* Vtw   = (__bf16*)(ws + 8388608);       // 8 MB  [B,H,HD,N] permuted
  __bf16* qkC   = (__bf16*)(ws + 16777216);      // 16 MB [8192][1024] Q|K
  __bf16* wqkv  = (__bf16*)(ws + 33554432);      // 1.5 MB
  __bf16* wproj = (__bf16*)(ws + 35127296);      // 0.5 MB
  __bf16* Ob    = (__bf16*)(ws + 35651584);      // 8 MB  context [m][512]
  // total 44,040,192 B

  cvt_all<<<5120, 256, 0, stream>>>(x, qkv_w, proj_w, xb, wqkv, wproj);
  gemm_qkv<<<dim3(12, 64), 256, 0, stream>>>(xb, wqkv, qkv_b, qkC, Vtw);
  attn_fused<<<dim3(16, 16), 512, 0, stream>>>(qkC, Vtw, Ob);
  gemm_proj<<<dim3(8, 64), 256, 0, stream>>>(Ob, wproj, proj_b, out);
}